// Round 14
// baseline (100.251 us; speedup 1.0000x reference)
//
#include <hip/hip_runtime.h>

#define NV 50257
#define NE 512
#define NH 1024
#define NB 1024
#define TSTEPS 10

typedef __bf16 bf16x8 __attribute__((ext_vector_type(8)));
typedef float  f32x4  __attribute__((ext_vector_type(4)));
typedef unsigned short u16;

// fp32 -> bf16 round-to-nearest-even
__device__ __forceinline__ u16 f2bf(float v) {
    unsigned u = __float_as_uint(v);
    unsigned r = u + 0x7fffu + ((u >> 16) & 1u);
    return (u16)(r >> 16);
}

// ---------------------------------------------------------------------------
// init: flag=0 (ws not re-poisoned between replays) + b2==0 detection.
// ---------------------------------------------------------------------------
__global__ void init_kernel(const float* __restrict__ b2,
                            unsigned* __restrict__ flag,
                            unsigned* __restrict__ flag_b2) {
    const int t = threadIdx.x;
    float4 v = ((const float4*)b2)[t];
    bool nz = (v.x != 0.0f) | (v.y != 0.0f) | (v.z != 0.0f) | (v.w != 0.0f);
    unsigned long long m = __ballot(nz);
    __shared__ unsigned sh;
    if (t == 0) sh = 0u;
    __syncthreads();
    if ((t & 63) == 0 && m != 0ull) atomicOr(&sh, 1u);
    __syncthreads();
    if (t == 0) { *flag = 0u; *flag_b2 = sh; }
}

// ---------------------------------------------------------------------------
// merged: blocks [0,512) convert W1 -> bf16; blocks [512,1024) embed+mask.
// ---------------------------------------------------------------------------
__global__ void prep_kernel(const float* __restrict__ W1, u16* __restrict__ w1b,
                            const int* __restrict__ tok,
                            const float* __restrict__ table,
                            const float* __restrict__ mask,
                            u16* __restrict__ ebf) {
    const int b = blockIdx.x;
    if (b < 512) {                       // W1 convert, n4 = 512*1024/4
        int i = b * 256 + threadIdx.x;
        float4 v = ((const float4*)W1)[i];
        ushort4 o;
        o.x = f2bf(v.x); o.y = f2bf(v.y); o.z = f2bf(v.z); o.w = f2bf(v.w);
        ((ushort4*)w1b)[i] = o;
    } else {                             // embedding gather + dropout mask
        int i = (b - 512) * 256 + threadIdx.x;   // n4 = 1024*512/4
        int bb = i / (NE / 4);
        int c = i % (NE / 4);
        float4 t = ((const float4*)(table + (size_t)tok[bb] * NE))[c];
        float4 m = ((const float4*)mask)[i];
        ushort4 o;
        o.x = f2bf(t.x * m.x); o.y = f2bf(t.y * m.y);
        o.z = f2bf(t.z * m.z); o.w = f2bf(t.w * m.w);
        ((ushort4*)ebf)[i] = o;
    }
}

// ---------------------------------------------------------------------------
// spike-path weight converts (merged W2 + fc_W), runs iff flag != 0
// ---------------------------------------------------------------------------
__global__ void cvt_cond_kernel(const unsigned* __restrict__ flag,
                                const float* __restrict__ W2, u16* __restrict__ w2b,
                                const float* __restrict__ fcW, u16* __restrict__ fcwb) {
    if (*flag == 0u) return;
    const int b = blockIdx.x;
    if (b < 512) {
        for (int i = b * 256 + threadIdx.x; i < NH * NH / 4; i += 512 * 256) {
            float4 v = ((const float4*)W2)[i];
            ushort4 o;
            o.x = f2bf(v.x); o.y = f2bf(v.y); o.z = f2bf(v.z); o.w = f2bf(v.w);
            ((ushort4*)w2b)[i] = o;
        }
    } else {
        for (int i = (b - 512) * 256 + threadIdx.x; i < NV * NH / 4; i += 2048 * 256) {
            float4 v = ((const float4*)fcW)[i];
            ushort4 o;
            o.x = f2bf(v.x); o.y = f2bf(v.y); o.z = f2bf(v.z); o.w = f2bf(v.w);
            ((ushort4*)fcwb)[i] = o;
        }
    }
}

// ---------------------------------------------------------------------------
// y[v] = fc_b[v] + 10 * dot(b2, fc_W[v,:]) — persistent 2048 blocks, wave per
// column, grid-stride (cheap drain when disabled). Runs iff spikes==0 AND b2!=0.
// ---------------------------------------------------------------------------
__global__ void matvec_fc_kernel(const unsigned* __restrict__ flag,
                                 const unsigned* __restrict__ flag_b2,
                                 const float* __restrict__ b2,
                                 const float* __restrict__ fcW,
                                 const float* __restrict__ fc_b,
                                 float* __restrict__ y) {
    if (*flag != 0u || *flag_b2 == 0u) return;
    const int wid = (blockIdx.x * 256 + threadIdx.x) >> 6;
    const int l = threadIdx.x & 63;
    const float4* bb = (const float4*)b2;
    for (int col = wid; col < NV; col += 2048 * 4) {
        const float4* row = (const float4*)(fcW + (size_t)col * NH);
        float s = 0.0f;
#pragma unroll
        for (int it = 0; it < NH / 256; ++it) {
            float4 v = row[it * 64 + l];
            float4 b = bb[it * 64 + l];
            s += v.x * b.x + v.y * b.y + v.z * b.z + v.w * b.w;
        }
#pragma unroll
        for (int off = 32; off > 0; off >>= 1) s += __shfl_down(s, off);
        if (l == 0) y[col] = fc_b[col] + (float)TSTEPS * s;
    }
}

// ---------------------------------------------------------------------------
// zero-spike outputs, merged (runs iff flag == 0):
//   blocks [0,512): outbuf = 10*b2 broadcast
//   blocks [512,...): linear[b,v] = src[v]; src = y (b2!=0) else fc_b
// ---------------------------------------------------------------------------
__global__ void bcast_merged_kernel(const unsigned* __restrict__ flag,
                                    const unsigned* __restrict__ flag_b2,
                                    const float* __restrict__ b2,
                                    const float* __restrict__ y,
                                    const float* __restrict__ fc_b,
                                    float* __restrict__ outbuf,
                                    float* __restrict__ linear) {
    if (*flag != 0u) return;
    const int b = blockIdx.x;
    if (b < 512) {
        int i0 = b * 256 + threadIdx.x;
        const int n4 = NB * NH / 4;
        for (int i = i0; i < n4; i += 512 * 256) {
            int h4 = i & (NH / 4 - 1);
            float4 v = ((const float4*)b2)[h4];
            v.x *= (float)TSTEPS; v.y *= (float)TSTEPS;
            v.z *= (float)TSTEPS; v.w *= (float)TSTEPS;
            ((float4*)outbuf)[i] = v;
        }
    } else {
        const float* __restrict__ src = (*flag_b2 != 0u) ? y : fc_b;
        const int idx = b - 512;                 // 0 .. 50*128-1
        const int c0 = (idx % 50) * 1024;        // 50 chunks of 1024 cols
        const int r0 = (idx / 50) * 8;           // 8 rows per block
        const int t = threadIdx.x;
        float vy[4];
#pragma unroll
        for (int k = 0; k < 4; ++k) {
            int c = c0 + t + k * 256;
            vy[k] = (c < NV) ? src[c] : 0.0f;
        }
#pragma unroll
        for (int r = 0; r < 8; ++r) {
            float* dst = linear + (size_t)(r0 + r) * NV;
#pragma unroll
            for (int k = 0; k < 4; ++k) {
                int c = c0 + t + k * 256;
                if (c < NV) dst[c] = vy[k];
            }
        }
    }
}

// ---------------------------------------------------------------------------
// gemm1 + LIF fused: delta1 = ebf@W1b^T + b1 computed in registers, LIF
// recurrence applied in the epilogue -> hbf (bf16) + spike flag. No delta1
// materialization (saves the node + 20 MB of round-trip traffic).
// GEMM core = round-9 pipeline (counted vmcnt, DEPTH=3, fragment-linear LDS,
// XCD-grouped 1D grid; determinism-proven). M=NB, N=NH, K=NE fixed.
// ---------------------------------------------------------------------------
__global__ __launch_bounds__(256)
void gemm1_lif_kernel(const u16* __restrict__ Abf, const u16* __restrict__ Bbf,
                      const float* __restrict__ bias,
                      const float* __restrict__ hidden,
                      const float* __restrict__ mask_lif,
                      const float* __restrict__ thr_p,
                      const float* __restrict__ leak_p,
                      u16* __restrict__ hbf,
                      unsigned* __restrict__ flag) {
    constexpr int TBM = 128, TBN = 128, NWAVE = 4;
    constexpr int AU = TBM / 16, BU = TBN / 16;
    constexpr int PER = (AU + BU) / NWAVE;
    constexpr int MF = 4, NF = TBN / 32;
    constexpr int DEPTH = 3;
    const int M = NB, N = NH, K = NE;

    __shared__ u16 sA[DEPTH][AU * 512];
    __shared__ u16 sB[DEPTH][BU * 512];

    const int i = blockIdx.x;
    const int xcd = i & 7;
    const int rb  = (i >> 3) & 7;
    const int p   = ((i >> 6) << 3) + xcd;
    if (p * TBN >= N) return;
    const int bm = rb * TBM;
    const int bn = p * TBN;

    const int tid = threadIdx.x;
    const int w = tid >> 6;
    const int l = tid & 63;
    const int wr16 = (w >> 1) * MF;
    const int wc16 = (w & 1) * NF;
    const int lrow = l & 15;
    const int lk8 = (l >> 4) * 8;
    const int l8 = l * 8;

    f32x4 acc[MF][NF];
#pragma unroll
    for (int m = 0; m < MF; ++m)
#pragma unroll
        for (int n = 0; n < NF; ++n)
#pragma unroll
            for (int q = 0; q < 4; ++q) acc[m][n][q] = 0.0f;

    const int NT = K / 32;

    auto stage = [&](int buf, int k0) {
#pragma unroll
        for (int s = 0; s < PER; ++s) {
            const int c = w * PER + s;
            if (c < AU) {
                const int row = bm + c * 16 + lrow;
                __builtin_amdgcn_global_load_lds(Abf + (size_t)row * K + k0 + lk8,
                                                 &sA[buf][c * 512], 16, 0, 0);
            } else {
                const int u = c - AU;
                int row = bn + u * 16 + lrow; if (row >= N) row = N - 1;
                __builtin_amdgcn_global_load_lds(Bbf + (size_t)row * K + k0 + lk8,
                                                 &sB[buf][u * 512], 16, 0, 0);
            }
        }
    };

    stage(0, 0);
    stage(1, 32);

    int cur = 0;
    for (int t = 0; t < NT; ++t) {
        if (t + 1 < NT) {
            asm volatile("s_waitcnt vmcnt(%0)" :: "n"(PER) : "memory");
        } else {
            asm volatile("s_waitcnt vmcnt(0)" ::: "memory");
        }
        __builtin_amdgcn_sched_barrier(0);
        __builtin_amdgcn_s_barrier();
        __builtin_amdgcn_sched_barrier(0);

        if (t + 2 < NT) {
            int nb = cur + 2; if (nb >= DEPTH) nb -= DEPTH;
            stage(nb, (t + 2) * 32);
        }

        bf16x8 ah[MF], bh[NF];
#pragma unroll
        for (int m = 0; m < MF; ++m)
            ah[m] = *(const bf16x8*)&sA[cur][(wr16 + m) * 512 + l8];
#pragma unroll
        for (int n = 0; n < NF; ++n)
            bh[n] = *(const bf16x8*)&sB[cur][(wc16 + n) * 512 + l8];

#pragma unroll
        for (int m = 0; m < MF; ++m)
#pragma unroll
            for (int n = 0; n < NF; ++n)
                acc[m][n] = __builtin_amdgcn_mfma_f32_16x16x32_bf16(ah[m], bh[n], acc[m][n], 0, 0, 0);

        __builtin_amdgcn_sched_barrier(0);
        cur = (cur + 1 == DEPTH) ? 0 : cur + 1;
    }

    // epilogue: LIF recurrence on d = acc + b1, write hbf + spike flag.
    // C/D layout: col = l&15, row = (l>>4)*4 + reg.
    const float thr = thr_p[0];
    const float leak = leak_p[0];
    const int lq = (l >> 4) * 4;
    const int wrow = bm + (w >> 1) * 64;
    const int wcol = bn + (w & 1) * (NF * 16);
    bool nz = false;
#pragma unroll
    for (int n = 0; n < NF; ++n) {
        const int gcol = wcol + n * 16 + (l & 15);
        const float bb = bias[gcol];
#pragma unroll
        for (int m = 0; m < MF; ++m) {
            const int grow = wrow + m * 16 + lq;
#pragma unroll
            for (int q = 0; q < 4; ++q) {
                const size_t off = (size_t)(grow + q) * NH + gcol;
                float d = acc[m][n][q] + bb;
                float mem_s = hidden[off];
                float cnt = 0.0f;
#pragma unroll
                for (int ts = 0; ts < TSTEPS; ++ts) {
                    float mem = leak * mem_s + d;
                    float s = ((mem / thr - 1.0f) > 0.0f) ? 1.0f : 0.0f;
                    mem_s = mem - thr * s;
                    cnt += s;
                }
                float v = cnt * mask_lif[off];
                nz |= (v != 0.0f);
                hbf[off] = f2bf(v);
            }
        }
    }
    if (nz) atomicOr(flag, 1u);
}

// ---------------------------------------------------------------------------
// bf16 x bf16 MFMA GEMM (round-9 pipeline, determinism-proven) — spike path.
// ---------------------------------------------------------------------------
template<int TBM, int TBN, int NWAVE>
__device__ __forceinline__
void gemm_pipe2_body(const u16* __restrict__ Abf, const u16* __restrict__ Bbf,
                     const float* __restrict__ bias, float bias_scale,
                     float* __restrict__ C, u16* __restrict__ Cb,
                     int M, int N, int K) {
    constexpr int AU = TBM / 16;
    constexpr int BU = TBN / 16;
    constexpr int TOT = AU + BU;
    constexpr int PER = TOT / NWAVE;
    constexpr int MF = 4;
    constexpr int NF = TBN / 32;
    constexpr int DEPTH = 3;
    static_assert(TOT % NWAVE == 0, "unit split");
    static_assert(NWAVE == 4 && TBM == 128, "wave tiling: 2x2 waves");

    __shared__ u16 sA[DEPTH][AU * 512];
    __shared__ u16 sB[DEPTH][BU * 512];

    const int i = blockIdx.x;
    const int xcd = i & 7;
    const int rb  = (i >> 3) & 7;
    const int p   = ((i >> 6) << 3) + xcd;
    if (p * TBN >= N) return;
    const int bm = rb * TBM;
    const int bn = p * TBN;

    const int tid = threadIdx.x;
    const int w = tid >> 6;
    const int l = tid & 63;
    const int wr16 = (w >> 1) * MF;
    const int wc16 = (w & 1) * NF;
    const int lrow = l & 15;
    const int lk8 = (l >> 4) * 8;
    const int l8 = l * 8;

    f32x4 acc[MF][NF];
#pragma unroll
    for (int m = 0; m < MF; ++m)
#pragma unroll
        for (int n = 0; n < NF; ++n)
#pragma unroll
            for (int q = 0; q < 4; ++q) acc[m][n][q] = 0.0f;

    const int NT = K / 32;

    auto stage = [&](int buf, int k0) {
#pragma unroll
        for (int s = 0; s < PER; ++s) {
            const int c = w * PER + s;
            if (c < AU) {
                const int row = bm + c * 16 + lrow;
                __builtin_amdgcn_global_load_lds(Abf + (size_t)row * K + k0 + lk8,
                                                 &sA[buf][c * 512], 16, 0, 0);
            } else {
                const int u = c - AU;
                int row = bn + u * 16 + lrow; if (row >= N) row = N - 1;
                __builtin_amdgcn_global_load_lds(Bbf + (size_t)row * K + k0 + lk8,
                                                 &sB[buf][u * 512], 16, 0, 0);
            }
        }
    };

    stage(0, 0);
    stage(1, 32);

    int cur = 0;
    for (int t = 0; t < NT; ++t) {
        if (t + 1 < NT) {
            asm volatile("s_waitcnt vmcnt(%0)" :: "n"(PER) : "memory");
        } else {
            asm volatile("s_waitcnt vmcnt(0)" ::: "memory");
        }
        __builtin_amdgcn_sched_barrier(0);
        __builtin_amdgcn_s_barrier();
        __builtin_amdgcn_sched_barrier(0);

        if (t + 2 < NT) {
            int nb = cur + 2; if (nb >= DEPTH) nb -= DEPTH;
            stage(nb, (t + 2) * 32);
        }

        bf16x8 ah[MF], bh[NF];
#pragma unroll
        for (int m = 0; m < MF; ++m)
            ah[m] = *(const bf16x8*)&sA[cur][(wr16 + m) * 512 + l8];
#pragma unroll
        for (int n = 0; n < NF; ++n)
            bh[n] = *(const bf16x8*)&sB[cur][(wc16 + n) * 512 + l8];

#pragma unroll
        for (int m = 0; m < MF; ++m)
#pragma unroll
            for (int n = 0; n < NF; ++n)
                acc[m][n] = __builtin_amdgcn_mfma_f32_16x16x32_bf16(ah[m], bh[n], acc[m][n], 0, 0, 0);

        __builtin_amdgcn_sched_barrier(0);
        cur = (cur + 1 == DEPTH) ? 0 : cur + 1;
    }

    const int lq = (l >> 4) * 4;
    const int wrow = bm + (w >> 1) * 64;
    const int wcol = bn + (w & 1) * (NF * 16);
#pragma unroll
    for (int n = 0; n < NF; ++n) {
        const int gcol = wcol + n * 16 + (l & 15);
        if (gcol >= N) continue;
        const float bb = bias[gcol] * bias_scale;
#pragma unroll
        for (int m = 0; m < MF; ++m) {
            const int grow = wrow + m * 16 + lq;
#pragma unroll
            for (int q = 0; q < 4; ++q) {
                float v = acc[m][n][q] + bb;
                C[(size_t)(grow + q) * N + gcol] = v;
                if (Cb) Cb[(size_t)(grow + q) * N + gcol] = f2bf(v);
            }
        }
    }
}

__global__ __launch_bounds__(256)
void gemm_pipe2_128_cond(const unsigned* __restrict__ flag,
                         const u16* __restrict__ Abf, const u16* __restrict__ Bbf,
                         const float* __restrict__ bias, float bias_scale,
                         float* __restrict__ C, u16* __restrict__ Cb, int M, int N, int K) {
    if (*flag == 0u) return;
    gemm_pipe2_body<128, 128, 4>(Abf, Bbf, bias, bias_scale, C, Cb, M, N, K);
}

__global__ __launch_bounds__(256, 2)
void gemm_pipe2_256_cond(const unsigned* __restrict__ flag,
                         const u16* __restrict__ Abf, const u16* __restrict__ Bbf,
                         const float* __restrict__ bias, float bias_scale,
                         float* __restrict__ C, u16* __restrict__ Cb, int M, int N, int K) {
    if (*flag == 0u) return;
    gemm_pipe2_body<128, 256, 4>(Abf, Bbf, bias, bias_scale, C, Cb, M, N, K);
}

// ---------------------------------------------------------------------------
// fp32 fallback kernels (tiny-workspace safety net)
// ---------------------------------------------------------------------------
__global__ void embed_kernel(const int* __restrict__ tok,
                             const float* __restrict__ table,
                             const float* __restrict__ mask,
                             float* __restrict__ emb) {
    int i = blockIdx.x * blockDim.x + threadIdx.x;
    const int n4 = NB * NE / 4;
    if (i >= n4) return;
    int b = i / (NE / 4);
    int c = i % (NE / 4);
    float4 t = ((const float4*)(table + (size_t)tok[b] * NE))[c];
    float4 m = ((const float4*)mask)[i];
    float4 o;
    o.x = t.x * m.x; o.y = t.y * m.y; o.z = t.z * m.z; o.w = t.w * m.w;
    ((float4*)emb)[i] = o;
}

__global__ void lif_kernel(const float* __restrict__ delta1,
                           const float* __restrict__ hidden,
                           const float* __restrict__ mask_lif,
                           const float* __restrict__ thr_p,
                           const float* __restrict__ leak_p,
                           float* __restrict__ hsum) {
    int i = blockIdx.x * blockDim.x + threadIdx.x;
    if (i >= NB * NH) return;
    const float thr = thr_p[0];
    const float leak = leak_p[0];
    float d = delta1[i];
    float m = hidden[i];
    float cnt = 0.0f;
#pragma unroll
    for (int t = 0; t < TSTEPS; ++t) {
        float mem = leak * m + d;
        float s = ((mem / thr - 1.0f) > 0.0f) ? 1.0f : 0.0f;
        m = mem - thr * s;
        cnt += s;
    }
    hsum[i] = cnt * mask_lif[i];
}

#define BM 128
#define BN 128
#define BK 16

__global__ __launch_bounds__(256)
void gemm_nt(const float* __restrict__ A, const float* __restrict__ Bm,
             const float* __restrict__ bias, float bias_scale,
             float* __restrict__ C, int M, int N, int K) {
    __shared__ float As[BK][BM + 4];
    __shared__ float Bs[BK][BN + 4];

    const int tid = threadIdx.x;
    const int bm = blockIdx.y * BM;
    const int bn = blockIdx.x * BN;
    const int tx = tid & 15;
    const int ty = tid >> 4;
    const int tm = ty * 8;
    const int tn0 = tx * 4;
    const int tn1 = 64 + tx * 4;

    float acc[8][8];
#pragma unroll
    for (int i = 0; i < 8; ++i)
#pragma unroll
        for (int j = 0; j < 8; ++j) acc[i][j] = 0.0f;

    constexpr int LDA4 = BK / 4;

    for (int k0 = 0; k0 < K; k0 += BK) {
#pragma unroll
        for (int idx = tid; idx < BM * LDA4; idx += 256) {
            int m = idx / LDA4, c = idx % LDA4;
            float4 v = *(const float4*)(A + (size_t)(bm + m) * K + k0 + c * 4);
            As[c * 4 + 0][m] = v.x;
            As[c * 4 + 1][m] = v.y;
            As[c * 4 + 2][m] = v.z;
            As[c * 4 + 3][m] = v.w;
        }
#pragma unroll
        for (int idx = tid; idx < BN * LDA4; idx += 256) {
            int n = idx / LDA4, c = idx % LDA4;
            float4 v = make_float4(0.f, 0.f, 0.f, 0.f);
            int gn = bn + n;
            if (gn < N) v = *(const float4*)(Bm + (size_t)gn * K + k0 + c * 4);
            Bs[c * 4 + 0][n] = v.x;
            Bs[c * 4 + 1][n] = v.y;
            Bs[c * 4 + 2][n] = v.z;
            Bs[c * 4 + 3][n] = v.w;
        }
        __syncthreads();

#pragma unroll
        for (int k = 0; k < BK; ++k) {
            float4 a0 = *(const float4*)&As[k][tm];
            float4 a1 = *(const float4*)&As[k][tm + 4];
            float4 b0 = *(const float4*)&Bs[k][tn0];
            float4 b1 = *(const float4*)&Bs[k][tn1];
            float a[8] = {a0.x, a0.y, a0.z, a0.w, a1.x, a1.y, a1.z, a1.w};
            float bb[8] = {b0.x, b0.y, b0.z, b0.w, b1.x, b1.y, b1.z, b1.w};
#pragma unroll
            for (int i = 0; i < 8; ++i)
#pragma unroll
                for (int j = 0; j < 8; ++j)
                    acc[i][j] = fmaf(a[i], bb[j], acc[i][j]);
        }
        __syncthreads();
    }

#pragma unroll
    for (int i = 0; i < 8; ++i) {
        size_t row = (size_t)(bm + tm + i) * N;
#pragma unroll
        for (int j = 0; j < 8; ++j) {
            int gn = bn + ((j < 4) ? (tn0 + j) : (tn1 + j - 4));
            if (gn < N)
                C[row + gn] = acc[i][j] + bias[gn] * bias_scale;
        }
    }
}

// ---------------------------------------------------------------------------
static inline int grid1d(int N, int TBN) {
    int P = (N + TBN - 1) / TBN;
    int P8 = ((P + 7) / 8) * 8;
    return 8 * P8;                  // 8 row-blocks x padded panels
}

extern "C" void kernel_launch(void* const* d_in, const int* in_sizes, int n_in,
                              void* d_out, int out_size, void* d_ws, size_t ws_size,
                              hipStream_t stream) {
    const int*   tok      = (const int*)  d_in[0];
    const float* hidden   = (const float*)d_in[1];
    const float* table    = (const float*)d_in[2];
    const float* W1       = (const float*)d_in[3];
    const float* b1       = (const float*)d_in[4];
    const float* W2       = (const float*)d_in[5];
    const float* b2       = (const float*)d_in[6];
    const float* fc_W     = (const float*)d_in[7];
    const float* fc_b     = (const float*)d_in[8];
    const float* thr      = (const float*)d_in[9];
    const float* leak     = (const float*)d_in[10];
    const float* mask_emb = (const float*)d_in[11];
    const float* mask_lif = (const float*)d_in[12];

    float* linear = (float*)d_out;                   // [B,V]
    float* outbuf = (float*)d_out + (size_t)NB * NV; // [B,H]

    const size_t SZ_FLAG = 16;                   // two flags live here
    const size_t SZ_Y   = ((size_t)NV * 4 + 15) / 16 * 16;  // y[V]
    const size_t SZ_EB  = (size_t)NB * NE * 2;   // ebf
    const size_t SZ_HB  = (size_t)NB * NH * 2;   // hbf
    const size_t SZ_OB  = (size_t)NB * NH * 2;   // obf
    const size_t SZ_W1B = (size_t)NH * NE * 2;   // W1 bf16
    const size_t SZ_W2B = (size_t)NH * NH * 2;   // W2 bf16
    const size_t SZ_WB  = (size_t)NV * NH * 2;   // fc_W bf16 (~103 MB)
    const size_t need_bf = SZ_FLAG + SZ_Y + SZ_EB + SZ_HB + SZ_OB
                         + SZ_W1B + SZ_W2B + SZ_WB;

    char* p = (char*)d_ws;

    if (ws_size >= need_bf) {
        unsigned* flag    = (unsigned*)p;            // [0] spike, [1] b2-nonzero
        unsigned* flag_b2 = (unsigned*)p + 1;
        p += SZ_FLAG;
        float* y      = (float*)p;     p += SZ_Y;
        u16*   ebf    = (u16*)p;       p += SZ_EB;
        u16*   hbf    = (u16*)p;       p += SZ_HB;
        u16*   obf    = (u16*)p;       p += SZ_OB;
        u16*   w1b    = (u16*)p;       p += SZ_W1B;
        u16*   w2b    = (u16*)p;       p += SZ_W2B;
        u16*   fcwb   = (u16*)p;       p += SZ_WB;

        // flags (spike=0, b2-nonzero detect)
        init_kernel<<<1, 256, 0, stream>>>(b2, flag, flag_b2);
        // W1 convert + embedding (merged, 1024 blocks)
        prep_kernel<<<1024, 256, 0, stream>>>(W1, w1b, tok, table, mask_emb, ebf);
        // gemm1 + LIF fused -> hbf + spike flag (no delta1 materialization)
        gemm1_lif_kernel<<<grid1d(NH, 128), 256, 0, stream>>>(ebf, w1b, b1,
                                                              hidden, mask_lif,
                                                              thr, leak, hbf, flag);
        // ---- zero-spike fast path (flag == 0) ----
        matvec_fc_kernel<<<2048, 256, 0, stream>>>(flag, flag_b2, b2, fc_W, fc_b, y);
        bcast_merged_kernel<<<512 + 50 * (NB / 8), 256, 0, stream>>>(flag, flag_b2, b2,
                                                                     y, fc_b, outbuf, linear);
        // ---- spike path (flag != 0): full MFMA decode ----
        cvt_cond_kernel<<<2560, 256, 0, stream>>>(flag, W2, w2b, fc_W, fcwb);
        gemm_pipe2_128_cond<<<grid1d(NH, 128), 256, 0, stream>>>(flag, hbf, w2b, b2, (float)TSTEPS,
                                                                 outbuf, obf, NB, NH, NH);
        gemm_pipe2_256_cond<<<grid1d(NV, 256), 256, 0, stream>>>(flag, obf, fcwb, fc_b, 1.0f,
                                                                 linear, (u16*)nullptr, NB, NV, NH);
    } else {
        // ----- pure fp32 fallback -----
        float* emb    = (float*)p;  p += (size_t)NB * NE * 4;
        float* delta1 = (float*)p;  p += (size_t)NB * NH * 4;
        float* hsum   = (float*)p;

        int n4 = NB * NE / 4;
        embed_kernel<<<(n4 + 255) / 256, 256, 0, stream>>>(tok, table, mask_emb, emb);
        {
            dim3 grid(NH / BN, NB / BM);
            gemm_nt<<<grid, 256, 0, stream>>>(emb, W1, b1, 1.0f, delta1, NB, NH, NE);
        }
        {
            int n = NB * NH;
            lif_kernel<<<(n + 255) / 256, 256, 0, stream>>>(delta1, hidden, mask_lif,
                                                            thr, leak, hsum);
        }
        {
            dim3 grid(NH / BN, NB / BM);
            gemm_nt<<<grid, 256, 0, stream>>>(hsum, W2, b2, (float)TSTEPS, outbuf, NB, NH, NH);
        }
        {
            dim3 grid((NV + BN - 1) / BN, NB / BM);
            gemm_nt<<<grid, 256, 0, stream>>>(outbuf, fc_W, fc_b, 1.0f, linear, NB, NV, NH);
        }
    }
}

// Round 15
// 66.355 us; speedup vs baseline: 1.5108x; 1.5108x over previous
//
#include <hip/hip_runtime.h>

#define NV 50257
#define NE 512
#define NH 1024
#define NB 1024
#define TSTEPS 10

typedef __bf16 bf16x8 __attribute__((ext_vector_type(8)));
typedef float  f32x4  __attribute__((ext_vector_type(4)));
typedef unsigned short u16;

// fp32 -> bf16 round-to-nearest-even
__device__ __forceinline__ u16 f2bf(float v) {
    unsigned u = __float_as_uint(v);
    unsigned r = u + 0x7fffu + ((u >> 16) & 1u);
    return (u16)(r >> 16);
}

// ---------------------------------------------------------------------------
// prep (merged): block 0 additionally zeroes the spike flag and detects
// b2 == 0; blocks [0,512) convert W1 -> bf16; blocks [512,1024) embed+mask.
// ---------------------------------------------------------------------------
__global__ void prep_kernel(const float* __restrict__ W1, u16* __restrict__ w1b,
                            const int* __restrict__ tok,
                            const float* __restrict__ table,
                            const float* __restrict__ mask,
                            u16* __restrict__ ebf,
                            const float* __restrict__ b2,
                            unsigned* __restrict__ flag,
                            unsigned* __restrict__ flag_b2) {
    const int b = blockIdx.x;
    if (b == 0) {   // flag init + b2==0 detection (all 1024 b2 elems)
        const int t = threadIdx.x;
        float4 v = ((const float4*)b2)[t];
        bool nz = (v.x != 0.0f) | (v.y != 0.0f) | (v.z != 0.0f) | (v.w != 0.0f);
        unsigned long long m = __ballot(nz);
        __shared__ unsigned sh;
        if (t == 0) sh = 0u;
        __syncthreads();
        if ((t & 63) == 0 && m != 0ull) atomicOr(&sh, 1u);
        __syncthreads();
        if (t == 0) { *flag = 0u; *flag_b2 = sh; }
    }
    if (b < 512) {                       // W1 convert, n4 = 512*1024/4
        int i = b * 256 + threadIdx.x;
        float4 v = ((const float4*)W1)[i];
        ushort4 o;
        o.x = f2bf(v.x); o.y = f2bf(v.y); o.z = f2bf(v.z); o.w = f2bf(v.w);
        ((ushort4*)w1b)[i] = o;
    } else {                             // embedding gather + dropout mask
        int i = (b - 512) * 256 + threadIdx.x;   // n4 = 1024*512/4
        int bb = i / (NE / 4);
        int c = i % (NE / 4);
        float4 t = ((const float4*)(table + (size_t)tok[bb] * NE))[c];
        float4 m = ((const float4*)mask)[i];
        ushort4 o;
        o.x = f2bf(t.x * m.x); o.y = f2bf(t.y * m.y);
        o.z = f2bf(t.z * m.z); o.w = f2bf(t.w * m.w);
        ((ushort4*)ebf)[i] = o;
    }
}

// ---------------------------------------------------------------------------
// LIF recurrence -> hsum (fp32, for the rare spike path) + spike flag.
// 1024 blocks (full-GPU elementwise — round-14 fusion onto 64 blocks regressed).
// ---------------------------------------------------------------------------
__global__ void lif_flag_kernel(const float* __restrict__ delta1,
                                const float* __restrict__ hidden,
                                const float* __restrict__ mask_lif,
                                const float* __restrict__ thr_p,
                                const float* __restrict__ leak_p,
                                float* __restrict__ hsum,
                                unsigned* __restrict__ flag) {
    int i = blockIdx.x * blockDim.x + threadIdx.x;
    if (i >= NB * NH / 4) return;
    const float thr = thr_p[0];
    const float leak = leak_p[0];
    float4 d4 = ((const float4*)delta1)[i];
    float4 m4 = ((const float4*)hidden)[i];
    float4 k4 = ((const float4*)mask_lif)[i];
    float dd[4] = {d4.x, d4.y, d4.z, d4.w};
    float mm[4] = {m4.x, m4.y, m4.z, m4.w};
    float kk[4] = {k4.x, k4.y, k4.z, k4.w};
    float vv[4];
    bool nz = false;
#pragma unroll
    for (int j = 0; j < 4; ++j) {
        float m = mm[j], cnt = 0.0f;
#pragma unroll
        for (int t = 0; t < TSTEPS; ++t) {
            float mem = leak * m + dd[j];
            float s = ((mem / thr - 1.0f) > 0.0f) ? 1.0f : 0.0f;
            m = mem - thr * s;
            cnt += s;
        }
        vv[j] = cnt * kk[j];
        nz |= (vv[j] != 0.0f);
    }
    float4 o; o.x = vv[0]; o.y = vv[1]; o.z = vv[2]; o.w = vv[3];
    ((float4*)hsum)[i] = o;
    if (nz) atomicOr(flag, 1u);          // device-scope; wave-coalesced (G12)
}

// ---------------------------------------------------------------------------
// y[v] = fc_b[v] + 10 * dot(b2, fc_W[v,:]) — persistent 2048 blocks, wave per
// column, grid-stride (cheap drain when disabled). Runs iff spikes==0 AND b2!=0.
// ---------------------------------------------------------------------------
__global__ void matvec_fc_kernel(const unsigned* __restrict__ flag,
                                 const unsigned* __restrict__ flag_b2,
                                 const float* __restrict__ b2,
                                 const float* __restrict__ fcW,
                                 const float* __restrict__ fc_b,
                                 float* __restrict__ y) {
    if (*flag != 0u || *flag_b2 == 0u) return;
    const int wid = (blockIdx.x * 256 + threadIdx.x) >> 6;
    const int l = threadIdx.x & 63;
    const float4* bb = (const float4*)b2;
    for (int col = wid; col < NV; col += 2048 * 4) {
        const float4* row = (const float4*)(fcW + (size_t)col * NH);
        float s = 0.0f;
#pragma unroll
        for (int it = 0; it < NH / 256; ++it) {
            float4 v = row[it * 64 + l];
            float4 b = bb[it * 64 + l];
            s += v.x * b.x + v.y * b.y + v.z * b.z + v.w * b.w;
        }
#pragma unroll
        for (int off = 32; off > 0; off >>= 1) s += __shfl_down(s, off);
        if (l == 0) y[col] = fc_b[col] + (float)TSTEPS * s;
    }
}

// ---------------------------------------------------------------------------
// zero-spike outputs, merged (runs iff flag == 0):
//   blocks [0,512): outbuf = 10*b2 broadcast
//   blocks [512,...): linear[b,v] = src[v]; src = y (b2!=0) else fc_b
// ---------------------------------------------------------------------------
__global__ void bcast_merged_kernel(const unsigned* __restrict__ flag,
                                    const unsigned* __restrict__ flag_b2,
                                    const float* __restrict__ b2,
                                    const float* __restrict__ y,
                                    const float* __restrict__ fc_b,
                                    float* __restrict__ outbuf,
                                    float* __restrict__ linear) {
    if (*flag != 0u) return;
    const int b = blockIdx.x;
    if (b < 512) {
        int i0 = b * 256 + threadIdx.x;
        const int n4 = NB * NH / 4;
        for (int i = i0; i < n4; i += 512 * 256) {
            int h4 = i & (NH / 4 - 1);
            float4 v = ((const float4*)b2)[h4];
            v.x *= (float)TSTEPS; v.y *= (float)TSTEPS;
            v.z *= (float)TSTEPS; v.w *= (float)TSTEPS;
            ((float4*)outbuf)[i] = v;
        }
    } else {
        const float* __restrict__ src = (*flag_b2 != 0u) ? y : fc_b;
        const int idx = b - 512;                 // 0 .. 50*128-1
        const int c0 = (idx % 50) * 1024;        // 50 chunks of 1024 cols
        const int r0 = (idx / 50) * 8;           // 8 rows per block
        const int t = threadIdx.x;
        float vy[4];
#pragma unroll
        for (int k = 0; k < 4; ++k) {
            int c = c0 + t + k * 256;
            vy[k] = (c < NV) ? src[c] : 0.0f;
        }
#pragma unroll
        for (int r = 0; r < 8; ++r) {
            float* dst = linear + (size_t)(r0 + r) * NV;
#pragma unroll
            for (int k = 0; k < 4; ++k) {
                int c = c0 + t + k * 256;
                if (c < NV) dst[c] = vy[k];
            }
        }
    }
}

// ---------------------------------------------------------------------------
// bf16 x bf16 MFMA GEMM (round-9 pipeline, determinism-proven: counted vmcnt,
// DEPTH=3, fragment-linear LDS (0 bank conflicts), XCD-grouped 1D grid).
// Used unconditionally for gemm1 (delta1 = ebf @ W1b^T + b1).
// ---------------------------------------------------------------------------
__global__ __launch_bounds__(256)
void gemm_pipe2_128(const u16* __restrict__ Abf, const u16* __restrict__ Bbf,
                    const float* __restrict__ bias, float bias_scale,
                    float* __restrict__ C, int M, int N, int K) {
    constexpr int TBM = 128, TBN = 128, NWAVE = 4;
    constexpr int AU = TBM / 16, BU = TBN / 16;
    constexpr int PER = (AU + BU) / NWAVE;
    constexpr int MF = 4, NF = TBN / 32;
    constexpr int DEPTH = 3;

    __shared__ u16 sA[DEPTH][AU * 512];
    __shared__ u16 sB[DEPTH][BU * 512];

    const int i = blockIdx.x;
    const int xcd = i & 7;
    const int rb  = (i >> 3) & 7;
    const int p   = ((i >> 6) << 3) + xcd;
    if (p * TBN >= N) return;
    const int bm = rb * TBM;
    const int bn = p * TBN;

    const int tid = threadIdx.x;
    const int w = tid >> 6;
    const int l = tid & 63;
    const int wr16 = (w >> 1) * MF;
    const int wc16 = (w & 1) * NF;
    const int lrow = l & 15;
    const int lk8 = (l >> 4) * 8;
    const int l8 = l * 8;

    f32x4 acc[MF][NF];
#pragma unroll
    for (int m = 0; m < MF; ++m)
#pragma unroll
        for (int n = 0; n < NF; ++n)
#pragma unroll
            for (int q = 0; q < 4; ++q) acc[m][n][q] = 0.0f;

    const int NT = K / 32;

    auto stage = [&](int buf, int k0) {
#pragma unroll
        for (int s = 0; s < PER; ++s) {
            const int c = w * PER + s;
            if (c < AU) {
                const int row = bm + c * 16 + lrow;
                __builtin_amdgcn_global_load_lds(Abf + (size_t)row * K + k0 + lk8,
                                                 &sA[buf][c * 512], 16, 0, 0);
            } else {
                const int u = c - AU;
                int row = bn + u * 16 + lrow; if (row >= N) row = N - 1;
                __builtin_amdgcn_global_load_lds(Bbf + (size_t)row * K + k0 + lk8,
                                                 &sB[buf][u * 512], 16, 0, 0);
            }
        }
    };

    stage(0, 0);
    stage(1, 32);

    int cur = 0;
    for (int t = 0; t < NT; ++t) {
        if (t + 1 < NT) {
            asm volatile("s_waitcnt vmcnt(%0)" :: "n"(PER) : "memory");
        } else {
            asm volatile("s_waitcnt vmcnt(0)" ::: "memory");
        }
        __builtin_amdgcn_sched_barrier(0);
        __builtin_amdgcn_s_barrier();
        __builtin_amdgcn_sched_barrier(0);

        if (t + 2 < NT) {
            int nb = cur + 2; if (nb >= DEPTH) nb -= DEPTH;
            stage(nb, (t + 2) * 32);
        }

        bf16x8 ah[MF], bh[NF];
#pragma unroll
        for (int m = 0; m < MF; ++m)
            ah[m] = *(const bf16x8*)&sA[cur][(wr16 + m) * 512 + l8];
#pragma unroll
        for (int n = 0; n < NF; ++n)
            bh[n] = *(const bf16x8*)&sB[cur][(wc16 + n) * 512 + l8];

#pragma unroll
        for (int m = 0; m < MF; ++m)
#pragma unroll
            for (int n = 0; n < NF; ++n)
                acc[m][n] = __builtin_amdgcn_mfma_f32_16x16x32_bf16(ah[m], bh[n], acc[m][n], 0, 0, 0);

        __builtin_amdgcn_sched_barrier(0);
        cur = (cur + 1 == DEPTH) ? 0 : cur + 1;
    }

    const int lq = (l >> 4) * 4;
    const int wrow = bm + (w >> 1) * 64;
    const int wcol = bn + (w & 1) * (NF * 16);
#pragma unroll
    for (int n = 0; n < NF; ++n) {
        const int gcol = wcol + n * 16 + (l & 15);
        if (gcol >= N) continue;
        const float bb = bias[gcol] * bias_scale;
#pragma unroll
        for (int m = 0; m < MF; ++m) {
            const int grow = wrow + m * 16 + lq;
#pragma unroll
            for (int q = 0; q < 4; ++q)
                C[(size_t)(grow + q) * N + gcol] = acc[m][n][q] + bb;
        }
    }
}

// ---------------------------------------------------------------------------
// fp32 NT GEMM body: C = A*B^T + bias*scale. Used by the (never-taken on
// this data, but correct) spike path and the tiny-workspace fallback.
// ---------------------------------------------------------------------------
#define BM 128
#define BN 128
#define BK 16

__device__ __forceinline__
void gemm_nt_body(const float* __restrict__ A, const float* __restrict__ Bm,
                  const float* __restrict__ bias, float bias_scale,
                  float* __restrict__ C, int M, int N, int K) {
    __shared__ float As[BK][BM + 4];
    __shared__ float Bs[BK][BN + 4];

    const int tid = threadIdx.x;
    const int bm = blockIdx.y * BM;
    const int bn = blockIdx.x * BN;
    const int tx = tid & 15;
    const int ty = tid >> 4;
    const int tm = ty * 8;
    const int tn0 = tx * 4;
    const int tn1 = 64 + tx * 4;

    float acc[8][8];
#pragma unroll
    for (int i = 0; i < 8; ++i)
#pragma unroll
        for (int j = 0; j < 8; ++j) acc[i][j] = 0.0f;

    constexpr int LDA4 = BK / 4;

    for (int k0 = 0; k0 < K; k0 += BK) {
#pragma unroll
        for (int idx = tid; idx < BM * LDA4; idx += 256) {
            int m = idx / LDA4, c = idx % LDA4;
            float4 v = *(const float4*)(A + (size_t)(bm + m) * K + k0 + c * 4);
            As[c * 4 + 0][m] = v.x;
            As[c * 4 + 1][m] = v.y;
            As[c * 4 + 2][m] = v.z;
            As[c * 4 + 3][m] = v.w;
        }
#pragma unroll
        for (int idx = tid; idx < BN * LDA4; idx += 256) {
            int n = idx / LDA4, c = idx % LDA4;
            float4 v = make_float4(0.f, 0.f, 0.f, 0.f);
            int gn = bn + n;
            if (gn < N) v = *(const float4*)(Bm + (size_t)gn * K + k0 + c * 4);
            Bs[c * 4 + 0][n] = v.x;
            Bs[c * 4 + 1][n] = v.y;
            Bs[c * 4 + 2][n] = v.z;
            Bs[c * 4 + 3][n] = v.w;
        }
        __syncthreads();

#pragma unroll
        for (int k = 0; k < BK; ++k) {
            float4 a0 = *(const float4*)&As[k][tm];
            float4 a1 = *(const float4*)&As[k][tm + 4];
            float4 b0 = *(const float4*)&Bs[k][tn0];
            float4 b1 = *(const float4*)&Bs[k][tn1];
            float a[8] = {a0.x, a0.y, a0.z, a0.w, a1.x, a1.y, a1.z, a1.w};
            float bb[8] = {b0.x, b0.y, b0.z, b0.w, b1.x, b1.y, b1.z, b1.w};
#pragma unroll
            for (int i = 0; i < 8; ++i)
#pragma unroll
                for (int j = 0; j < 8; ++j)
                    acc[i][j] = fmaf(a[i], bb[j], acc[i][j]);
        }
        __syncthreads();
    }

#pragma unroll
    for (int i = 0; i < 8; ++i) {
        size_t row = (size_t)(bm + tm + i) * N;
#pragma unroll
        for (int j = 0; j < 8; ++j) {
            int gn = bn + ((j < 4) ? (tn0 + j) : (tn1 + j - 4));
            if (gn < N)
                C[row + gn] = acc[i][j] + bias[gn] * bias_scale;
        }
    }
}

__global__ __launch_bounds__(256)
void gemm_nt(const float* __restrict__ A, const float* __restrict__ Bm,
             const float* __restrict__ bias, float bias_scale,
             float* __restrict__ C, int M, int N, int K) {
    gemm_nt_body(A, Bm, bias, bias_scale, C, M, N, K);
}

__global__ __launch_bounds__(256)
void gemm_nt_cond(const unsigned* __restrict__ flag,
                  const float* __restrict__ A, const float* __restrict__ Bm,
                  const float* __restrict__ bias, float bias_scale,
                  float* __restrict__ C, int M, int N, int K) {
    if (*flag == 0u) return;     // uniform early-exit before any barrier
    gemm_nt_body(A, Bm, bias, bias_scale, C, M, N, K);
}

// ---------------------------------------------------------------------------
// fp32 fallback helpers (tiny-workspace safety net)
// ---------------------------------------------------------------------------
__global__ void embed_kernel(const int* __restrict__ tok,
                             const float* __restrict__ table,
                             const float* __restrict__ mask,
                             float* __restrict__ emb) {
    int i = blockIdx.x * blockDim.x + threadIdx.x;
    const int n4 = NB * NE / 4;
    if (i >= n4) return;
    int b = i / (NE / 4);
    int c = i % (NE / 4);
    float4 t = ((const float4*)(table + (size_t)tok[b] * NE))[c];
    float4 m = ((const float4*)mask)[i];
    float4 o;
    o.x = t.x * m.x; o.y = t.y * m.y; o.z = t.z * m.z; o.w = t.w * m.w;
    ((float4*)emb)[i] = o;
}

__global__ void lif_kernel(const float* __restrict__ delta1,
                           const float* __restrict__ hidden,
                           const float* __restrict__ mask_lif,
                           const float* __restrict__ thr_p,
                           const float* __restrict__ leak_p,
                           float* __restrict__ hsum) {
    int i = blockIdx.x * blockDim.x + threadIdx.x;
    if (i >= NB * NH) return;
    const float thr = thr_p[0];
    const float leak = leak_p[0];
    float d = delta1[i];
    float m = hidden[i];
    float cnt = 0.0f;
#pragma unroll
    for (int t = 0; t < TSTEPS; ++t) {
        float mem = leak * m + d;
        float s = ((mem / thr - 1.0f) > 0.0f) ? 1.0f : 0.0f;
        m = mem - thr * s;
        cnt += s;
    }
    hsum[i] = cnt * mask_lif[i];
}

// ---------------------------------------------------------------------------
static inline int grid1d(int N, int TBN) {
    int P = (N + TBN - 1) / TBN;
    int P8 = ((P + 7) / 8) * 8;
    return 8 * P8;                  // 8 row-blocks x padded panels
}

extern "C" void kernel_launch(void* const* d_in, const int* in_sizes, int n_in,
                              void* d_out, int out_size, void* d_ws, size_t ws_size,
                              hipStream_t stream) {
    const int*   tok      = (const int*)  d_in[0];
    const float* hidden   = (const float*)d_in[1];
    const float* table    = (const float*)d_in[2];
    const float* W1       = (const float*)d_in[3];
    const float* b1       = (const float*)d_in[4];
    const float* W2       = (const float*)d_in[5];
    const float* b2       = (const float*)d_in[6];
    const float* fc_W     = (const float*)d_in[7];
    const float* fc_b     = (const float*)d_in[8];
    const float* thr      = (const float*)d_in[9];
    const float* leak     = (const float*)d_in[10];
    const float* mask_emb = (const float*)d_in[11];
    const float* mask_lif = (const float*)d_in[12];

    float* linear = (float*)d_out;                   // [B,V]
    float* outbuf = (float*)d_out + (size_t)NB * NV; // [B,H]

    const size_t SZ_FLAG = 16;                   // two flags
    const size_t SZ_Y    = ((size_t)NV * 4 + 15) / 16 * 16;  // y[V]
    const size_t SZ_EB   = (size_t)NB * NE * 2;  // ebf
    const size_t SZ_D1   = (size_t)NB * NH * 4;  // delta1 fp32
    const size_t SZ_HS   = (size_t)NB * NH * 4;  // hsum fp32
    const size_t SZ_W1B  = (size_t)NH * NE * 2;  // W1 bf16
    const size_t need_bf = SZ_FLAG + SZ_Y + SZ_EB + SZ_D1 + SZ_HS + SZ_W1B;

    char* p = (char*)d_ws;

    if (ws_size >= need_bf) {
        unsigned* flag    = (unsigned*)p;            // [0] spike, [1] b2-nonzero
        unsigned* flag_b2 = (unsigned*)p + 1;
        p += SZ_FLAG;
        float* y      = (float*)p;     p += SZ_Y;
        u16*   ebf    = (u16*)p;       p += SZ_EB;
        float* delta1 = (float*)p;     p += SZ_D1;
        float* hsum   = (float*)p;     p += SZ_HS;
        u16*   w1b    = (u16*)p;       p += SZ_W1B;

        // 1: prep (flags + W1 cvt + embed)
        prep_kernel<<<1024, 256, 0, stream>>>(W1, w1b, tok, table, mask_emb, ebf,
                                              b2, flag, flag_b2);
        // 2: delta1 = ebf @ w1b^T + b1   (MFMA pipeline)
        gemm_pipe2_128<<<grid1d(NH, 128), 256, 0, stream>>>(ebf, w1b, b1, 1.0f,
                                                            delta1, NB, NH, NE);
        // 3: LIF -> hsum (fp32) + spike flag (full-GPU elementwise)
        {
            int n = NB * NH / 4;
            lif_flag_kernel<<<(n + 255) / 256, 256, 0, stream>>>(delta1, hidden, mask_lif,
                                                                 thr, leak, hsum, flag);
        }
        // 4: zero-spike + b2!=0: y = fc_b + 10*(b2 @ fc_W^T)  (drain otherwise)
        matvec_fc_kernel<<<2048, 256, 0, stream>>>(flag, flag_b2, b2, fc_W, fc_b, y);
        // 5: zero-spike outputs (outbuf + linear), at the write ceiling
        bcast_merged_kernel<<<512 + 50 * (NB / 8), 256, 0, stream>>>(flag, flag_b2, b2,
                                                                     y, fc_b, outbuf, linear);
        // 6-7: spike path (flag != 0): fp32 decode (correct; never taken on
        // this data, so plain gemm_nt is fine — drains cheaply otherwise)
        {
            dim3 g1(NH / BN, NB / BM);
            gemm_nt_cond<<<g1, 256, 0, stream>>>(flag, hsum, W2, b2, (float)TSTEPS,
                                                 outbuf, NB, NH, NH);
            dim3 g2((NV + BN - 1) / BN, NB / BM);
            gemm_nt_cond<<<g2, 256, 0, stream>>>(flag, outbuf, fc_W, fc_b, 1.0f,
                                                 linear, NB, NV, NH);
        }
    } else {
        // ----- pure fp32 fallback -----
        float* emb    = (float*)p;  p += (size_t)NB * NE * 4;
        float* delta1 = (float*)p;  p += (size_t)NB * NH * 4;
        float* hsum   = (float*)p;

        int n4 = NB * NE / 4;
        embed_kernel<<<(n4 + 255) / 256, 256, 0, stream>>>(tok, table, mask_emb, emb);
        {
            dim3 grid(NH / BN, NB / BM);
            gemm_nt<<<grid, 256, 0, stream>>>(emb, W1, b1, 1.0f, delta1, NB, NH, NE);
        }
        {
            int n = NB * NH;
            lif_kernel<<<(n + 255) / 256, 256, 0, stream>>>(delta1, hidden, mask_lif,
                                                            thr, leak, hsum);
        }
        {
            dim3 grid(NH / BN, NB / BM);
            gemm_nt<<<grid, 256, 0, stream>>>(hsum, W2, b2, (float)TSTEPS, outbuf, NB, NH, NH);
        }
        {
            dim3 grid((NV + BN - 1) / BN, NB / BM);
            gemm_nt<<<grid, 256, 0, stream>>>(outbuf, fc_W, fc_b, 1.0f, linear, NB, NV, NH);
        }
    }
}